// Round 5
// baseline (327.516 us; speedup 1.0000x reference)
//
#include <hip/hip_runtime.h>
#include <math.h>

// Quantized causal attention on int8 MFMA — R5.
// R5 changes vs R4 (passed, 264us total: main 129us, VALUBusy 47 / Mfma 9 /
// occ 20 -> latency/barrier-bound):
//  1. Software-pipelined staging in attn_main: tile kt+1's K8/V8T + consts are
//     prefetched into REGISTERS during tile kt's compute; only ds_write sits
//     between barriers. Hides ~200-900cyc global latency under compute.
//  2. PV bias folded out: cumulative group-sum CGS[bh][g][d] precomputed in
//     prep_vsum; epilogue adds CGS[kt_end] once (saves 1 op/el/tile + vsC).
//  3. prep_sums + prep_v fused into one launch (independent work).
//  4. Phase-1 exp2 terms tree-summed (ILP).

#define S_LEN 2048
#define BATCH 2
#define NH    16
#define HD    128
#define RSTR  4096   // floats between seq positions
#define SCALE2 (0.08838834764831845f * 1.4426950408889634f)   // (1/sqrt(128))/ln2
#define EXP2F(x) __builtin_amdgcn_exp2f(x)

typedef int v4i __attribute__((ext_vector_type(4)));
#define MFMA16(a,b,c) __builtin_amdgcn_mfma_i32_16x16x64_i8((a),(b),(c),0,0,0)

// ws byte offsets (total ~17.1 MB)
#define WS_K8   0u
#define WS_V8T  (8u*1024u*1024u)
#define WS_SQ   (16u*1024u*1024u)
#define WS_SK   (WS_SQ + 256u*1024u)
#define WS_GSV  (WS_SK + 256u*1024u)
#define WS_VSUM (WS_GSV + 256u*1024u)
#define WS_CGS  (WS_VSUM + 64u*1024u)

__device__ __forceinline__ int sbsum(unsigned p) {
    return (int)(signed char)(p) + (int)(signed char)(p>>8)
         + (int)(signed char)(p>>16) + (int)(signed char)(p>>24);
}

// ---- fused pre-kernel: Q/K token sums + K int8 pack  |  V transpose + GSV ----
__global__ __launch_bounds__(256) void prep_pack(
    const float* __restrict__ Q, const float* __restrict__ K, const float* __restrict__ V,
    signed char* __restrict__ K8, float* __restrict__ SQs, float* __restrict__ SKs,
    signed char* __restrict__ V8T, float* __restrict__ GSV)
{
    __shared__ int v8i[128*33];
    const int tid = threadIdx.x;
    const int bx  = blockIdx.x;
    if (bx < 16384) {
        const int tensor = bx >> 13;
        const int idx = (bx & 8191)*256 + tid;
        const float* src = tensor ? K : Q;
        int tau = idx >> 5, dg = idx & 31;
        float4 x = *(const float4*)(src + (size_t)tau*128 + 4*dg);
        float ssum = x.x + x.y + x.z + x.w;
        #pragma unroll
        for (int off = 16; off >= 1; off >>= 1) ssum += __shfl_xor(ssum, off);
        if (tensor) {
            int a=(int)x.x, b2=(int)x.y, c=(int)x.z, d=(int)x.w;
            ((int*)K8)[(size_t)tau*32 + dg] = (a&255)|((b2&255)<<8)|((c&255)<<16)|((d&255)<<24);
            if ((tid & 31) == 0) SKs[tau] = ssum;
        } else {
            if ((tid & 31) == 0) SQs[tau] = ssum;
        }
    } else {
        const int bid = bx - 16384;
        const int bh = bid & 31, ck = bid >> 5;   // ck = 128-t chunk = v-group
        const int b = bh >> 4, h = bh & 15;
        const int t0 = ck * 128;
        const int boff = b*2048 + h*128;
        #pragma unroll
        for (int it = 0; it < 16; ++it) {
            int idx = tid + it*256;
            int t = idx >> 5, dw = idx & 31;
            float4 x = *(const float4*)(V + (size_t)(t0+t)*RSTR + boff + 4*dw);
            int a=(int)x.x, b2=(int)x.y, c=(int)x.z, d=(int)x.w;
            v8i[t*33 + dw] = (a&255)|((b2&255)<<8)|((c&255)<<16)|((d&255)<<24);
        }
        __syncthreads();
        #pragma unroll
        for (int it = 0; it < 4; ++it) {
            int j = tid + it*256;
            int tg = j & 31, dw = j >> 5;
            unsigned r0 = (unsigned)v8i[(4*tg+0)*33 + dw];
            unsigned r1 = (unsigned)v8i[(4*tg+1)*33 + dw];
            unsigned r2 = (unsigned)v8i[(4*tg+2)*33 + dw];
            unsigned r3 = (unsigned)v8i[(4*tg+3)*33 + dw];
            unsigned x01 = __builtin_amdgcn_perm(r1, r0, 0x05010400u);
            unsigned x23 = __builtin_amdgcn_perm(r3, r2, 0x05010400u);
            unsigned y01 = __builtin_amdgcn_perm(r1, r0, 0x07030602u);
            unsigned y23 = __builtin_amdgcn_perm(r3, r2, 0x07030602u);
            unsigned p[4];
            p[0] = __builtin_amdgcn_perm(x23, x01, 0x05040100u);
            p[1] = __builtin_amdgcn_perm(x23, x01, 0x07060302u);
            p[2] = __builtin_amdgcn_perm(y23, y01, 0x05040100u);
            p[3] = __builtin_amdgcn_perm(y23, y01, 0x07060302u);
            int s[4];
            #pragma unroll
            for (int jj = 0; jj < 4; ++jj) {
                int d = 4*dw + jj;
                *(int*)(V8T + ((size_t)bh*128 + d)*2048 + t0 + 4*tg) = (int)p[jj];
                s[jj] = sbsum(p[jj]);
            }
            #pragma unroll
            for (int off = 1; off < 32; off <<= 1) {
                #pragma unroll
                for (int jj = 0; jj < 4; ++jj) s[jj] += __shfl_xor(s[jj], off);
            }
            if (tg == 0) {
                #pragma unroll
                for (int jj = 0; jj < 4; ++jj)
                    GSV[((size_t)bh*16 + ck)*128 + 4*dw + jj] = (float)s[jj];
            }
        }
    }
}

// ---- pre-kernel: full-row V-dequant sum + cumulative PV bias table ----
__global__ __launch_bounds__(256) void prep_vsum(
    const float* __restrict__ GSV, const float* __restrict__ VSC,
    const float* __restrict__ VMN, float* __restrict__ VSUM, float* __restrict__ CGS)
{
    int idx = blockIdx.x*256 + threadIdx.x;   // 4096
    int bh = idx >> 7, d = idx & 127;
    int b = bh >> 4, h = bh & 15;
    float acc = 0.f, accb = 0.f;
    for (int g = 0; g < 16; ++g) {
        float gs = GSV[((size_t)bh*16 + g)*128 + d];
        int vi = ((g*BATCH + b)*NH + h)*HD + d;
        float vs = VSC[vi], vm = VMN[vi];
        acc  = fmaf(vs, gs, fmaf(128.0f, vm, acc));
        accb = fmaf(128.0f*vs, gs, fmaf(16384.0f, vm, accb));
        CGS[((size_t)bh*16 + g)*128 + d] = accb;
    }
    VSUM[bh*128 + d] = acc;
}

// ---- main kernel ----
__global__ __launch_bounds__(256, 2) void attn_main(
    const float* __restrict__ Q,
    const signed char* __restrict__ K8, const signed char* __restrict__ V8T,
    const float* __restrict__ QMN, const float* __restrict__ QSC,
    const float* __restrict__ KMN, const float* __restrict__ KSC,
    const float* __restrict__ VMN, const float* __restrict__ VSC,
    const float* __restrict__ SQs, const float* __restrict__ SKs,
    const float* __restrict__ GSV, const float* __restrict__ VSUM,
    const float* __restrict__ CGS,
    const int* __restrict__ CAUSAL, float* __restrict__ OUT)
{
    __shared__ __align__(16) signed char q8s[64*144];   // [q][d] int8
    __shared__ __align__(16) signed char k8s[128*144];  // [t][d] int8
    __shared__ __align__(16) signed char v8s[128*144];  // [d][t] int8 (transposed)
    __shared__ __align__(16) signed char pcs[64*144];   // [q][t] code' int8
    __shared__ float rs_c1[64], rs_c2[64], rs_c3[64];
    __shared__ float rs_mx[64], rs_den[64], rs_mn[64];
    __shared__ float rs_u1[64], rs_w1[64], rs_psc[64], rs_pmn[64];
    __shared__ float ktA[128], ktB[128], ktC[128];      // ks*S2, km*S2, sk8
    __shared__ float vsA[128], vsB[128];                // vs, vm

    const int tid  = threadIdx.x;
    const int w    = tid >> 6;
    const int lane = tid & 63;
    const int n    = lane & 15;
    const int quad = lane >> 4;
    const int bhi  = blockIdx.x & 31;
    const int qt   = 31 - (int)(blockIdx.x >> 5);   // heavy tiles first
    const int b    = bhi >> 4, h = bhi & 15;
    const int causal = *CAUSAL;
    const int s0   = qt * 64;
    const int boff = b*2048 + h*128;
    const v4i vzero = {0,0,0,0};
    const v4i ones  = {0x01010101,0x01010101,0x01010101,0x01010101};

    // ---- stage Q tile (float -> int8 LDS) + per-row consts ----
    #pragma unroll
    for (int it = 0; it < 8; ++it) {
        int idx = tid + it*256;
        int row = idx >> 5, d4 = (idx & 31) << 2;
        float4 x = *(const float4*)(Q + (size_t)(s0+row)*RSTR + boff + d4);
        int a=(int)x.x, b2=(int)x.y, c=(int)x.z, d=(int)x.w;
        *(int*)(q8s + row*144 + d4) = (a&255)|((b2&255)<<8)|((c&255)<<16)|((d&255)<<24);
    }
    if (tid < 64) {
        int si = (s0 + tid)*32 + bhi;
        float qs = QSC[si], qm = QMN[si];
        rs_c1[tid] = qs; rs_c2[tid] = qm;
        rs_c3[tid] = fmaf(qs, SQs[si], 128.0f*qm);
    }

    const int kt_end = causal ? ((s0 + 63) >> 7) : 15;

    // ---- phase-1 initial stage (tile 0) ----
    #pragma unroll
    for (int it = 0; it < 4; ++it) {
        int idx = tid + it*256;
        int trow = idx >> 3, doff = (idx & 7) << 4;
        *(uint4*)(k8s + trow*144 + doff) =
            *(const uint4*)(K8 + ((size_t)trow*32 + bhi)*128 + doff);
    }
    if (tid < 128) {
        int si = tid*32 + bhi;
        ktA[tid] = KSC[si]*SCALE2; ktB[tid] = KMN[si]*SCALE2; ktC[tid] = SKs[si];
    }
    __syncthreads();

    float c1r[4], c2r[4], c3r[4]; int qgr[4];
    #pragma unroll
    for (int r = 0; r < 4; ++r) {
        int qq = 16*w + 4*quad + r;
        c1r[r] = rs_c1[qq]; c2r[r] = rs_c2[qq]; c3r[r] = rs_c3[qq];
        qgr[r] = s0 + qq;
    }
    v4i a0p = *(const v4i*)(q8s + (16*w + n)*144 + 16*quad);
    v4i a1p = *(const v4i*)(q8s + (16*w + n)*144 + 64 + 16*quad);

    float m[4], l[4], mn[4];
    #pragma unroll
    for (int r = 0; r < 4; ++r) { m[r] = -INFINITY; l[r] = 0.f; mn[r] = INFINITY; }

#define P1_COMPUTE(MASKED, T0G)                                                  \
  do {                                                                           \
    float tmax[4], sarr[8][4];                                                   \
    _Pragma("unroll")                                                            \
    for (int r = 0; r < 4; ++r) tmax[r] = -INFINITY;                             \
    _Pragma("unroll")                                                            \
    for (int tb = 0; tb < 8; ++tb) {                                             \
        v4i b0 = *(const v4i*)(k8s + (16*tb + n)*144 + 16*quad);                 \
        v4i b1 = *(const v4i*)(k8s + (16*tb + n)*144 + 64 + 16*quad);            \
        v4i acc = MFMA16(a0p, b0, vzero);                                        \
        acc = MFMA16(a1p, b1, acc);                                              \
        int tl = 16*tb + n;                                                      \
        float kA = ktA[tl], kB = ktB[tl], kC = ktC[tl];                          \
        _Pragma("unroll")                                                        \
        for (int r = 0; r < 4; ++r) {                                            \
            float Sf = (float)acc[r];                                            \
            float sv = fmaf(kA, fmaf(c1r[r], Sf, c2r[r]*kC), kB*c3r[r]);         \
            if (MASKED) sv = ((T0G) + tl > qgr[r]) ? -INFINITY : sv;             \
            sarr[tb][r] = sv;                                                    \
            tmax[r] = fmaxf(tmax[r], sv);                                        \
            mn[r] = fminf(mn[r], sv);                                            \
        }                                                                        \
    }                                                                            \
    _Pragma("unroll")                                                            \
    for (int r = 0; r < 4; ++r) {                                                \
        float mm = fmaxf(m[r], tmax[r]);                                         \
        if (mm > -INFINITY) {                                                    \
            float e0 = EXP2F(sarr[0][r]-mm) + EXP2F(sarr[1][r]-mm);              \
            float e1 = EXP2F(sarr[2][r]-mm) + EXP2F(sarr[3][r]-mm);              \
            float e2 = EXP2F(sarr[4][r]-mm) + EXP2F(sarr[5][r]-mm);              \
            float e3 = EXP2F(sarr[6][r]-mm) + EXP2F(sarr[7][r]-mm);              \
            l[r] = fmaf(l[r], EXP2F(m[r]-mm), (e0+e1)+(e2+e3));                  \
            m[r] = mm;                                                           \
        }                                                                        \
    }                                                                            \
  } while (0)

    // ================= Phase 1 (pipelined) =================
    for (int kt = 0; ; ++kt) {
        const int t0g = kt * 128;
        const bool has_next = kt < kt_end;
        uint4 pk[4]; float nA = 0.f, nB = 0.f, nC = 0.f;
        if (has_next) {
            const int t0n = t0g + 128;
            #pragma unroll
            for (int it = 0; it < 4; ++it) {
                int idx = tid + it*256;
                int trow = idx >> 3, doff = (idx & 7) << 4;
                pk[it] = *(const uint4*)(K8 + ((size_t)(t0n+trow)*32 + bhi)*128 + doff);
            }
            if (tid < 128) {
                int si = (t0n + tid)*32 + bhi;
                nA = KSC[si]; nB = KMN[si]; nC = SKs[si];
            }
        }
        if (causal && kt == kt_end) P1_COMPUTE(true, t0g);
        else                        P1_COMPUTE(false, t0g);
        if (!has_next) break;
        __syncthreads();
        #pragma unroll
        for (int it = 0; it < 4; ++it) {
            int idx = tid + it*256;
            int trow = idx >> 3, doff = (idx & 7) << 4;
            *(uint4*)(k8s + trow*144 + doff) = pk[it];
        }
        if (tid < 128) { ktA[tid] = nA*SCALE2; ktB[tid] = nB*SCALE2; ktC[tid] = nC; }
        __syncthreads();
    }

    // reduce stats across the 16 col-lanes
    #pragma unroll
    for (int r = 0; r < 4; ++r) {
        #pragma unroll
        for (int off = 1; off < 16; off <<= 1) {
            float m2 = __shfl_xor(m[r], off);
            float l2 = __shfl_xor(l[r], off);
            float n2 = __shfl_xor(mn[r], off);
            float mm = fmaxf(m[r], m2);
            if (mm > -INFINITY) l[r] = l[r]*EXP2F(m[r]-mm) + l2*EXP2F(m2-mm);
            m[r] = mm;
            mn[r] = fminf(mn[r], n2);
        }
        if (n == 0) {
            int qq = 16*w + 4*quad + r;
            rs_mx[qq] = m[r]; rs_den[qq] = l[r]; rs_mn[qq] = mn[r];
        }
    }
    __syncthreads();
    if (tid < 64) {
        float mx = rs_mx[tid], den = rs_den[tid], mnv = rs_mn[tid];
        float invd = 1.0f/den;
        int s = s0 + tid;
        bool hasmask = (causal != 0) && (s < S_LEN-1);
        float pmin = hasmask ? 0.0f : EXP2F(mnv - mx)*invd;
        float psc  = (invd - pmin)/255.0f + 1e-12f;
        float ipsc = 1.0f/psc;
        rs_u1[tid] = invd*ipsc; rs_w1[tid] = -pmin*ipsc;
        rs_psc[tid] = psc; rs_pmn[tid] = pmin;
    }

    // ---- phase-2 initial stage (tile 0; k8s overwrite safe: barrier above) ----
    #pragma unroll
    for (int it = 0; it < 4; ++it) {
        int idx = tid + it*256;
        int trow = idx >> 3, doff = (idx & 7) << 4;
        *(uint4*)(k8s + trow*144 + doff) =
            *(const uint4*)(K8 + ((size_t)trow*32 + bhi)*128 + doff);
        *(uint4*)(v8s + trow*144 + doff) =
            *(const uint4*)(V8T + ((size_t)bhi*128 + trow)*2048 + doff);
    }
    if (tid < 128) {
        int si = tid*32 + bhi;
        ktA[tid] = KSC[si]*SCALE2; ktB[tid] = KMN[si]*SCALE2; ktC[tid] = SKs[si];
    } else {
        int d = tid - 128;
        int vi = (b*NH + h)*HD + d;   // g = 0
        vsA[d] = VSC[vi]; vsB[d] = VMN[vi];
    }
    __syncthreads();

    float outa[4][8];
    #pragma unroll
    for (int r = 0; r < 4; ++r)
        #pragma unroll
        for (int db = 0; db < 8; ++db) outa[r][db] = 0.f;

#define P2_COMPUTE(MASKED, T0G)                                                  \
  do {                                                                           \
    _Pragma("unroll")                                                            \
    for (int rb = 0; rb < 2; ++rb) {                                             \
        int trow = 32*w + 16*rb;                                                 \
        v4i a0 = *(const v4i*)(k8s + (trow + n)*144 + 16*quad);                  \
        v4i a1 = *(const v4i*)(k8s + (trow + n)*144 + 64 + 16*quad);             \
        float ksr[4], kmr[4], skr[4];                                            \
        int tgb = (T0G) + trow + 4*quad;                                         \
        _Pragma("unroll")                                                        \
        for (int r = 0; r < 4; ++r) {                                            \
            int tl = trow + 4*quad + r;                                          \
            ksr[r] = ktA[tl]; kmr[r] = ktB[tl]; skr[r] = ktC[tl];                \
        }                                                                        \
        _Pragma("unroll")                                                        \
        for (int cb = 0; cb < 4; ++cb) {                                         \
            v4i b0 = *(const v4i*)(q8s + (16*cb + n)*144 + 16*quad);             \
            v4i b1 = *(const v4i*)(q8s + (16*cb + n)*144 + 64 + 16*quad);        \
            v4i acc = MFMA16(a0, b0, vzero);                                     \
            acc = MFMA16(a1, b1, acc);                                           \
            int qcol = 16*cb + n, qg = s0 + qcol;                                \
            float c1 = rs_c1[qcol], c2 = rs_c2[qcol], c3 = rs_c3[qcol];          \
            float mxq = rs_mx[qcol], u1 = rs_u1[qcol], w1 = rs_w1[qcol];         \
            int packed = 0;                                                      \
            _Pragma("unroll")                                                    \
            for (int r = 0; r < 4; ++r) {                                        \
                float Sf = (float)acc[r];                                        \
                float x = fmaf(ksr[r], fmaf(c1, Sf, c2*skr[r]),                  \
                               fmaf(kmr[r], c3, -mxq));                          \
                if (MASKED) x = (tgb + r > qg) ? -INFINITY : x;                  \
                float e = EXP2F(x);                                              \
                int ci = (int)rintf(fmaf(e, u1, w1));                            \
                packed |= ci << (8*r);                                           \
            }                                                                    \
            packed ^= 0x80808080;  /* code - 128 per byte */                     \
            *(int*)(pcs + qcol*144 + trow + 4*quad) = packed;                    \
        }                                                                        \
    }                                                                            \
    __syncthreads();                                                             \
    {                                                                            \
        v4i a0 = *(const v4i*)(pcs + (16*w + n)*144 + 16*quad);                  \
        v4i a1 = *(const v4i*)(pcs + (16*w + n)*144 + 64 + 16*quad);             \
        v4i c1a = MFMA16(a0, ones, vzero);                                       \
        c1a = MFMA16(a1, ones, c1a);                                             \
        float c1f[4];                                                            \
        _Pragma("unroll")                                                        \
        for (int r = 0; r < 4; ++r) c1f[r] = (float)c1a[r];                      \
        _Pragma("unroll")                                                        \
        for (int db = 0; db < 8; ++db) {                                         \
            v4i b0 = *(const v4i*)(v8s + (16*db + n)*144 + 16*quad);             \
            v4i b1 = *(const v4i*)(v8s + (16*db + n)*144 + 64 + 16*quad);        \
            v4i cv = MFMA16(a0, b0, vzero);                                      \
            cv = MFMA16(a1, b1, cv);                                             \
            int d = 16*db + n;                                                   \
            float vs = vsA[d], vm = vsB[d];                                      \
            _Pragma("unroll")                                                    \
            for (int r = 0; r < 4; ++r)                                          \
                outa[r][db] = fmaf(vs, (float)cv[r],                             \
                                   fmaf(vm, c1f[r], outa[r][db]));               \
        }                                                                        \
    }                                                                            \
  } while (0)

    // ================= Phase 2 (pipelined) =================
    for (int kt = 0; ; ++kt) {
        const int t0g = kt * 128;
        const bool has_next = kt < kt_end;
        uint4 pk[4], pv[4]; float nA = 0.f, nB = 0.f, nC = 0.f;
        if (has_next) {
            const int t0n = t0g + 128;
            #pragma unroll
            for (int it = 0; it < 4; ++it) {
                int idx = tid + it*256;
                int trow = idx >> 3, doff = (idx & 7) << 4;
                pk[it] = *(const uint4*)(K8 + ((size_t)(t0n+trow)*32 + bhi)*128 + doff);
                pv[it] = *(const uint4*)(V8T + ((size_t)bhi*128 + trow)*2048 + t0n + doff);
            }
            if (tid < 128) {
                int si = (t0n + tid)*32 + bhi;
                nA = KSC[si]; nB = KMN[si]; nC = SKs[si];
            } else {
                int d = tid - 128;
                int vi = (((kt+1)*BATCH + b)*NH + h)*HD + d;
                nA = VSC[vi]; nB = VMN[vi];
            }
        }
        if (causal && kt == kt_end) P2_COMPUTE(true, t0g);
        else                        P2_COMPUTE(false, t0g);
        if (!has_next) break;
        __syncthreads();   // all PV reads of v8s/pcs done
        #pragma unroll
        for (int it = 0; it < 4; ++it) {
            int idx = tid + it*256;
            int trow = idx >> 3, doff = (idx & 7) << 4;
            *(uint4*)(k8s + trow*144 + doff) = pk[it];
            *(uint4*)(v8s + trow*144 + doff) = pv[it];
        }
        if (tid < 128) { ktA[tid] = nA*SCALE2; ktB[tid] = nB*SCALE2; ktC[tid] = nC; }
        else           { int d = tid - 128; vsA[d] = nA; vsB[d] = nB; }
        __syncthreads();
    }

    // ---- epilogue: out = psc*(outa + CGS[kt_end]) + pmin*Vsum ----
    float pscr[4], pmnr[4];
    #pragma unroll
    for (int r = 0; r < 4; ++r) {
        int qq = 16*w + 4*quad + r;
        pscr[r] = rs_psc[qq]; pmnr[r] = rs_pmn[qq];
    }
    #pragma unroll
    for (int db = 0; db < 8; ++db) {
        int d = 16*db + n;
        float vsum = VSUM[bhi*128 + d];
        float cgs  = CGS[((size_t)bhi*16 + kt_end)*128 + d];
        #pragma unroll
        for (int r = 0; r < 4; ++r) {
            int s = s0 + 16*w + 4*quad + r;
            OUT[(size_t)s*RSTR + boff + d] = fmaf(pscr[r], outa[r][db] + cgs, pmnr[r]*vsum);
        }
    }
}

extern "C" void kernel_launch(void* const* d_in, const int* in_sizes, int n_in,
                              void* d_out, int out_size, void* d_ws, size_t ws_size,
                              hipStream_t stream) {
    (void)in_sizes; (void)n_in; (void)out_size; (void)ws_size;
    const float* Q   = (const float*)d_in[0];
    const float* K   = (const float*)d_in[1];
    const float* V   = (const float*)d_in[2];
    const float* QMN = (const float*)d_in[3];
    const float* QSC = (const float*)d_in[4];
    const float* KMN = (const float*)d_in[5];
    const float* KSC = (const float*)d_in[6];
    const float* VMN = (const float*)d_in[7];
    const float* VSC = (const float*)d_in[8];
    const int*   CS  = (const int*)d_in[9];
    float* out = (float*)d_out;

    char* ws = (char*)d_ws;
    signed char* K8  = (signed char*)(ws + WS_K8);
    signed char* V8T = (signed char*)(ws + WS_V8T);
    float* SQs  = (float*)(ws + WS_SQ);
    float* SKs  = (float*)(ws + WS_SK);
    float* GSVp = (float*)(ws + WS_GSV);
    float* VSUM = (float*)(ws + WS_VSUM);
    float* CGSp = (float*)(ws + WS_CGS);

    prep_pack<<<16384 + 512, 256, 0, stream>>>(Q, K, V, K8, SQs, SKs, V8T, GSVp);
    prep_vsum<<<16, 256, 0, stream>>>(GSVp, VSC, VMN, VSUM, CGSp);
    attn_main<<<1024, 256, 0, stream>>>(Q, K8, V8T, QMN, QSC, KMN, KSC, VMN, VSC,
                                        SQs, SKs, GSVp, VSUM, CGSp, CS, out);
}

// Round 6
// 251.918 us; speedup vs baseline: 1.3001x; 1.3001x over previous
//
#include <hip/hip_runtime.h>
#include <math.h>

// Quantized causal attention on int8 MFMA — R6.
// R5 post-mortem: register prefetch arrays (pk/pv) living across barriers were
// demoted to LDS (+16KB, promote-alloca) and scratch (+183MB WRITE_SIZE spills).
// R6 = R4 skeleton (129us main) + surgical cuts:
//  1. P2 Q-fragments (8 v4i) + per-q constants (24 f32) hoisted out of kt loop
//     (tile-invariant; unconditional init, read-only — like P1's a0p/a1p).
//  2. P2 QK A-operand (K rows) read DIRECT from global (each row used exactly
//     once per block in P2) — k8s LDS staging+reads removed from P2.
//  3. Requant: (int)rintf + shift/or  ->  x+2^23 magic round (RNE, == rintf)
//     + low-byte pack via 3x v_perm_b32 + 1 xor.
//  4. prep_vsum folded into attn_main (threads 128..255 compute VSUM/CGS rows
//     during softmax-stats phase); 2 kernel launches total.

#define S_LEN 2048
#define BATCH 2
#define NH    16
#define HD    128
#define RSTR  4096   // floats between seq positions
#define SCALE2 (0.08838834764831845f * 1.4426950408889634f)   // (1/sqrt(128))/ln2
#define EXP2F(x) __builtin_amdgcn_exp2f(x)

typedef int v4i __attribute__((ext_vector_type(4)));
#define MFMA16(a,b,c) __builtin_amdgcn_mfma_i32_16x16x64_i8((a),(b),(c),0,0,0)

// ws byte offsets (total ~16.8 MB)
#define WS_K8   0u
#define WS_V8T  (8u*1024u*1024u)
#define WS_SQ   (16u*1024u*1024u)
#define WS_SK   (WS_SQ + 256u*1024u)
#define WS_GSV  (WS_SK + 256u*1024u)

__device__ __forceinline__ int sbsum(unsigned p) {
    return (int)(signed char)(p) + (int)(signed char)(p>>8)
         + (int)(signed char)(p>>16) + (int)(signed char)(p>>24);
}

// ---- fused pre-kernel: Q/K token sums + K int8 pack  |  V transpose + GSV ----
__global__ __launch_bounds__(256) void prep_pack(
    const float* __restrict__ Q, const float* __restrict__ K, const float* __restrict__ V,
    signed char* __restrict__ K8, float* __restrict__ SQs, float* __restrict__ SKs,
    signed char* __restrict__ V8T, float* __restrict__ GSV)
{
    __shared__ int v8i[128*33];
    const int tid = threadIdx.x;
    const int bx  = blockIdx.x;
    if (bx < 16384) {
        const int tensor = bx >> 13;
        const int idx = (bx & 8191)*256 + tid;
        const float* src = tensor ? K : Q;
        int tau = idx >> 5, dg = idx & 31;
        float4 x = *(const float4*)(src + (size_t)tau*128 + 4*dg);
        float ssum = x.x + x.y + x.z + x.w;
        #pragma unroll
        for (int off = 16; off >= 1; off >>= 1) ssum += __shfl_xor(ssum, off);
        if (tensor) {
            int a=(int)x.x, b2=(int)x.y, c=(int)x.z, d=(int)x.w;
            ((int*)K8)[(size_t)tau*32 + dg] = (a&255)|((b2&255)<<8)|((c&255)<<16)|((d&255)<<24);
            if ((tid & 31) == 0) SKs[tau] = ssum;
        } else {
            if ((tid & 31) == 0) SQs[tau] = ssum;
        }
    } else {
        const int bid = bx - 16384;
        const int bh = bid & 31, ck = bid >> 5;   // ck = 128-t chunk = v-group
        const int b = bh >> 4, h = bh & 15;
        const int t0 = ck * 128;
        const int boff = b*2048 + h*128;
        #pragma unroll
        for (int it = 0; it < 16; ++it) {
            int idx = tid + it*256;
            int t = idx >> 5, dw = idx & 31;
            float4 x = *(const float4*)(V + (size_t)(t0+t)*RSTR + boff + 4*dw);
            int a=(int)x.x, b2=(int)x.y, c=(int)x.z, d=(int)x.w;
            v8i[t*33 + dw] = (a&255)|((b2&255)<<8)|((c&255)<<16)|((d&255)<<24);
        }
        __syncthreads();
        #pragma unroll
        for (int it = 0; it < 4; ++it) {
            int j = tid + it*256;
            int tg = j & 31, dw = j >> 5;
            unsigned r0 = (unsigned)v8i[(4*tg+0)*33 + dw];
            unsigned r1 = (unsigned)v8i[(4*tg+1)*33 + dw];
            unsigned r2 = (unsigned)v8i[(4*tg+2)*33 + dw];
            unsigned r3 = (unsigned)v8i[(4*tg+3)*33 + dw];
            unsigned x01 = __builtin_amdgcn_perm(r1, r0, 0x05010400u);
            unsigned x23 = __builtin_amdgcn_perm(r3, r2, 0x05010400u);
            unsigned y01 = __builtin_amdgcn_perm(r1, r0, 0x07030602u);
            unsigned y23 = __builtin_amdgcn_perm(r3, r2, 0x07030602u);
            unsigned p[4];
            p[0] = __builtin_amdgcn_perm(x23, x01, 0x05040100u);
            p[1] = __builtin_amdgcn_perm(x23, x01, 0x07060302u);
            p[2] = __builtin_amdgcn_perm(y23, y01, 0x05040100u);
            p[3] = __builtin_amdgcn_perm(y23, y01, 0x07060302u);
            int s[4];
            #pragma unroll
            for (int jj = 0; jj < 4; ++jj) {
                int d = 4*dw + jj;
                *(int*)(V8T + ((size_t)bh*128 + d)*2048 + t0 + 4*tg) = (int)p[jj];
                s[jj] = sbsum(p[jj]);
            }
            #pragma unroll
            for (int off = 1; off < 32; off <<= 1) {
                #pragma unroll
                for (int jj = 0; jj < 4; ++jj) s[jj] += __shfl_xor(s[jj], off);
            }
            if (tg == 0) {
                #pragma unroll
                for (int jj = 0; jj < 4; ++jj)
                    GSV[((size_t)bh*16 + ck)*128 + 4*dw + jj] = (float)s[jj];
            }
        }
    }
}

// ---- main kernel ----
__global__ __launch_bounds__(256, 2) void attn_main(
    const float* __restrict__ Q,
    const signed char* __restrict__ K8, const signed char* __restrict__ V8T,
    const float* __restrict__ QMN, const float* __restrict__ QSC,
    const float* __restrict__ KMN, const float* __restrict__ KSC,
    const float* __restrict__ VMN, const float* __restrict__ VSC,
    const float* __restrict__ SQs, const float* __restrict__ SKs,
    const float* __restrict__ GSV,
    const int* __restrict__ CAUSAL, float* __restrict__ OUT)
{
    __shared__ __align__(16) signed char q8s[64*144];   // [q][d] int8
    __shared__ __align__(16) signed char k8s[128*144];  // [t][d] int8 (phase 1 only)
    __shared__ __align__(16) signed char v8s[128*144];  // [d][t] int8 (transposed)
    __shared__ __align__(16) signed char pcs[64*144];   // [q][t] code' int8
    __shared__ float rs_c1[64], rs_c2[64], rs_c3[64];
    __shared__ float rs_mx[64], rs_den[64], rs_mn[64];
    __shared__ float rs_u1[64], rs_w1[64], rs_psc[64], rs_pmn[64];
    __shared__ float ktA[128], ktB[128], ktC[128];      // ks*S2, km*S2, sk8
    __shared__ float vsA[128], vsB[128];                // vs, vm (current group)
    __shared__ float vsumL[128], cgsL[128];             // in-block VSUM / CGS row

    const int tid  = threadIdx.x;
    const int w    = tid >> 6;
    const int lane = tid & 63;
    const int n    = lane & 15;
    const int quad = lane >> 4;
    const int bhi  = blockIdx.x & 31;
    const int qt   = 31 - (int)(blockIdx.x >> 5);   // heavy tiles first
    const int b    = bhi >> 4, h = bhi & 15;
    const int causal = *CAUSAL;
    const int s0   = qt * 64;
    const int boff = b*2048 + h*128;
    const v4i vzero = {0,0,0,0};
    const v4i ones  = {0x01010101,0x01010101,0x01010101,0x01010101};

    // ---- stage Q tile (float -> int8 LDS) + per-row consts ----
    #pragma unroll
    for (int it = 0; it < 8; ++it) {
        int idx = tid + it*256;
        int row = idx >> 5, d4 = (idx & 31) << 2;
        float4 x = *(const float4*)(Q + (size_t)(s0+row)*RSTR + boff + d4);
        int a=(int)x.x, b2=(int)x.y, c=(int)x.z, d=(int)x.w;
        *(int*)(q8s + row*144 + d4) = (a&255)|((b2&255)<<8)|((c&255)<<16)|((d&255)<<24);
    }
    if (tid < 64) {
        int si = (s0 + tid)*32 + bhi;
        float qs = QSC[si], qm = QMN[si];
        rs_c1[tid] = qs; rs_c2[tid] = qm;
        rs_c3[tid] = fmaf(qs, SQs[si], 128.0f*qm);
    }
    __syncthreads();

    const int kt_end = causal ? ((s0 + 63) >> 7) : 15;

    float c1r[4], c2r[4], c3r[4]; int qgr[4];
    #pragma unroll
    for (int r = 0; r < 4; ++r) {
        int qq = 16*w + 4*quad + r;
        c1r[r] = rs_c1[qq]; c2r[r] = rs_c2[qq]; c3r[r] = rs_c3[qq];
        qgr[r] = s0 + qq;
    }
    v4i a0p = *(const v4i*)(q8s + (16*w + n)*144 + 16*quad);
    v4i a1p = *(const v4i*)(q8s + (16*w + n)*144 + 64 + 16*quad);

    float m[4], l[4], mn[4];
    #pragma unroll
    for (int r = 0; r < 4; ++r) { m[r] = -INFINITY; l[r] = 0.f; mn[r] = INFINITY; }

    // ================= Phase 1: softmax stats (log2 domain) =================
#define P1_TILE(MASKED)                                                          \
  do {                                                                           \
    const int t0g = kt * 128;                                                    \
    __syncthreads();                                                             \
    _Pragma("unroll")                                                            \
    for (int it = 0; it < 4; ++it) {                                             \
        int idx = tid + it*256;                                                  \
        int trow = idx >> 3, doff = (idx & 7) << 4;                              \
        *(uint4*)(k8s + trow*144 + doff) =                                       \
            *(const uint4*)(K8 + ((size_t)(t0g+trow)*32 + bhi)*128 + doff);      \
    }                                                                            \
    if (tid < 128) {                                                             \
        int si = (t0g + tid)*32 + bhi;                                           \
        ktA[tid] = KSC[si]*SCALE2; ktB[tid] = KMN[si]*SCALE2; ktC[tid] = SKs[si];\
    }                                                                            \
    __syncthreads();                                                             \
    float tmax[4], sarr[8][4];                                                   \
    _Pragma("unroll")                                                            \
    for (int r = 0; r < 4; ++r) tmax[r] = -INFINITY;                             \
    _Pragma("unroll")                                                            \
    for (int tb = 0; tb < 8; ++tb) {                                             \
        v4i b0 = *(const v4i*)(k8s + (16*tb + n)*144 + 16*quad);                 \
        v4i b1 = *(const v4i*)(k8s + (16*tb + n)*144 + 64 + 16*quad);            \
        v4i acc = MFMA16(a0p, b0, vzero);                                        \
        acc = MFMA16(a1p, b1, acc);                                              \
        int tl = 16*tb + n;                                                      \
        float kA = ktA[tl], kB = ktB[tl], kC = ktC[tl];                          \
        _Pragma("unroll")                                                        \
        for (int r = 0; r < 4; ++r) {                                            \
            float Sf = (float)acc[r];                                            \
            float sv = fmaf(kA, fmaf(c1r[r], Sf, c2r[r]*kC), kB*c3r[r]);         \
            if (MASKED) sv = (t0g + tl > qgr[r]) ? -INFINITY : sv;               \
            sarr[tb][r] = sv;                                                    \
            tmax[r] = fmaxf(tmax[r], sv);                                        \
            mn[r] = fminf(mn[r], sv);                                            \
        }                                                                        \
    }                                                                            \
    _Pragma("unroll")                                                            \
    for (int r = 0; r < 4; ++r) {                                                \
        float mm = fmaxf(m[r], tmax[r]);                                         \
        if (mm > -INFINITY) {                                                    \
            float e0 = EXP2F(sarr[0][r]-mm) + EXP2F(sarr[1][r]-mm);              \
            float e1 = EXP2F(sarr[2][r]-mm) + EXP2F(sarr[3][r]-mm);              \
            float e2 = EXP2F(sarr[4][r]-mm) + EXP2F(sarr[5][r]-mm);              \
            float e3 = EXP2F(sarr[6][r]-mm) + EXP2F(sarr[7][r]-mm);              \
            l[r] = fmaf(l[r], EXP2F(m[r]-mm), (e0+e1)+(e2+e3));                  \
            m[r] = mm;                                                           \
        }                                                                        \
    }                                                                            \
  } while (0)

    {
        int kt;
        for (kt = 0; kt < kt_end; ++kt) P1_TILE(false);
        kt = kt_end;
        if (causal) P1_TILE(true); else P1_TILE(false);
    }

    // reduce stats across the 16 col-lanes
    #pragma unroll
    for (int r = 0; r < 4; ++r) {
        #pragma unroll
        for (int off = 1; off < 16; off <<= 1) {
            float m2 = __shfl_xor(m[r], off);
            float l2 = __shfl_xor(l[r], off);
            float n2 = __shfl_xor(mn[r], off);
            float mm = fmaxf(m[r], m2);
            if (mm > -INFINITY) l[r] = l[r]*EXP2F(m[r]-mm) + l2*EXP2F(m2-mm);
            m[r] = mm;
            mn[r] = fminf(mn[r], n2);
        }
        if (n == 0) {
            int qq = 16*w + 4*quad + r;
            rs_mx[qq] = m[r]; rs_den[qq] = l[r]; rs_mn[qq] = mn[r];
        }
    }
    __syncthreads();
    if (tid < 64) {
        float mx = rs_mx[tid], den = rs_den[tid], mnv = rs_mn[tid];
        float invd = 1.0f/den;
        int s = s0 + tid;
        bool hasmask = (causal != 0) && (s < S_LEN-1);
        float pmin = hasmask ? 0.0f : EXP2F(mnv - mx)*invd;
        float psc  = (invd - pmin)/255.0f + 1e-12f;
        float ipsc = 1.0f/psc;
        rs_u1[tid] = invd*ipsc; rs_w1[tid] = -pmin*ipsc;
        rs_psc[tid] = psc; rs_pmn[tid] = pmin;
    } else if (tid >= 128) {
        // in-block VSUM (full row) + CGS (cumulative to kt_end) for this bh
        int d = tid - 128;
        float vsum = 0.f, cgs = 0.f;
        #pragma unroll
        for (int g = 0; g < 16; ++g) {
            float gs = GSV[((size_t)bhi*16 + g)*128 + d];
            int vi = ((g*BATCH + b)*NH + h)*HD + d;
            float vs = VSC[vi], vm = VMN[vi];
            vsum = fmaf(vs, gs, fmaf(128.0f, vm, vsum));
            if (g <= kt_end) cgs = fmaf(128.0f*vs, gs, fmaf(16384.0f, vm, cgs));
        }
        vsumL[d] = vsum; cgsL[d] = cgs;
    }
    __syncthreads();

    // ---- hoist P2 tile-invariants: Q B-fragments + per-q constants ----
    v4i qb0[4], qb1[4];
    float qc1[4], qc2[4], qc3[4], qmxn[4], qu1[4], qw1[4];
    int qgq[4];
    #pragma unroll
    for (int cb = 0; cb < 4; ++cb) {
        int qcol = 16*cb + n;
        qb0[cb] = *(const v4i*)(q8s + qcol*144 + 16*quad);
        qb1[cb] = *(const v4i*)(q8s + qcol*144 + 64 + 16*quad);
        qc1[cb] = rs_c1[qcol]; qc2[cb] = rs_c2[qcol]; qc3[cb] = rs_c3[qcol];
        qmxn[cb] = -rs_mx[qcol]; qu1[cb] = rs_u1[qcol]; qw1[cb] = rs_w1[qcol];
        qgq[cb] = s0 + qcol;
    }

    // ================= Phase 2: requant + PV =================
    float outa[4][8];
    #pragma unroll
    for (int r = 0; r < 4; ++r)
        #pragma unroll
        for (int db = 0; db < 8; ++db) outa[r][db] = 0.f;

#define P2_TILE(MASKED)                                                          \
  do {                                                                           \
    const int t0g = kt * 128;                                                    \
    __syncthreads();   /* previous PV reads of v8s/pcs done */                   \
    _Pragma("unroll")                                                            \
    for (int it = 0; it < 4; ++it) {                                             \
        int idx = tid + it*256;                                                  \
        int trow = idx >> 3, doff = (idx & 7) << 4;                              \
        *(uint4*)(v8s + trow*144 + doff) =                                       \
            *(const uint4*)(V8T + ((size_t)bhi*128 + trow)*2048 + t0g + doff);   \
    }                                                                            \
    if (tid < 128) {                                                             \
        int si = (t0g + tid)*32 + bhi;                                           \
        ktA[tid] = KSC[si]*SCALE2; ktB[tid] = KMN[si]*SCALE2; ktC[tid] = SKs[si];\
    } else {                                                                     \
        int d = tid - 128;                                                       \
        int vi = ((kt*BATCH + b)*NH + h)*HD + d;                                 \
        vsA[d] = VSC[vi]; vsB[d] = VMN[vi];                                      \
    }                                                                            \
    __syncthreads();                                                             \
    _Pragma("unroll")                                                            \
    for (int rb = 0; rb < 2; ++rb) {                                             \
        int trow = 32*w + 16*rb;                                                 \
        const signed char* kp = K8 + ((size_t)(t0g+trow+n)*32 + bhi)*128         \
                                   + 16*quad;                                    \
        v4i a0 = *(const v4i*)kp;          /* A-operand direct from global */    \
        v4i a1 = *(const v4i*)(kp + 64);                                         \
        float ksr[4], kmr[4], skr[4];                                            \
        int tgb = t0g + trow + 4*quad;                                           \
        _Pragma("unroll")                                                        \
        for (int r = 0; r < 4; ++r) {                                            \
            int tl = trow + 4*quad + r;                                          \
            ksr[r] = ktA[tl]; kmr[r] = ktB[tl]; skr[r] = ktC[tl];                \
        }                                                                        \
        _Pragma("unroll")                                                        \
        for (int cb = 0; cb < 4; ++cb) {                                         \
            v4i acc = MFMA16(a0, qb0[cb], vzero);                                \
            acc = MFMA16(a1, qb1[cb], acc);                                      \
            int cby[4];                                                          \
            _Pragma("unroll")                                                    \
            for (int r = 0; r < 4; ++r) {                                        \
                float Sf = (float)acc[r];                                        \
                float x = fmaf(ksr[r], fmaf(qc1[cb], Sf, qc2[cb]*skr[r]),        \
                               fmaf(kmr[r], qc3[cb], qmxn[cb]));                 \
                if (MASKED) x = (tgb + r > qgq[cb]) ? -INFINITY : x;             \
                float e = EXP2F(x);                                              \
                float f = fmaf(e, qu1[cb], qw1[cb]) + 8388608.0f; /* RNE int */  \
                cby[r] = __float_as_int(f);                                      \
            }                                                                    \
            unsigned t01 = __builtin_amdgcn_perm((unsigned)cby[1],               \
                                                 (unsigned)cby[0], 0x00000400u); \
            unsigned t23 = __builtin_amdgcn_perm((unsigned)cby[3],               \
                                                 (unsigned)cby[2], 0x04000000u); \
            int packed = (int)(__builtin_amdgcn_perm(t23, t01, 0x07060100u)      \
                               ^ 0x80808080u);  /* code - 128 per byte */        \
            *(int*)(pcs + (16*cb + n)*144 + trow + 4*quad) = packed;             \
        }                                                                        \
    }                                                                            \
    __syncthreads();                                                             \
    {                                                                            \
        v4i a0 = *(const v4i*)(pcs + (16*w + n)*144 + 16*quad);                  \
        v4i a1 = *(const v4i*)(pcs + (16*w + n)*144 + 64 + 16*quad);             \
        v4i c1a = MFMA16(a0, ones, vzero);                                       \
        c1a = MFMA16(a1, ones, c1a);                                             \
        float c1f[4];                                                            \
        _Pragma("unroll")                                                        \
        for (int r = 0; r < 4; ++r) c1f[r] = (float)c1a[r];                      \
        _Pragma("unroll")                                                        \
        for (int db = 0; db < 8; ++db) {                                         \
            v4i b0 = *(const v4i*)(v8s + (16*db + n)*144 + 16*quad);             \
            v4i b1 = *(const v4i*)(v8s + (16*db + n)*144 + 64 + 16*quad);        \
            v4i cv = MFMA16(a0, b0, vzero);                                      \
            cv = MFMA16(a1, b1, cv);                                             \
            int d = 16*db + n;                                                   \
            float vs = vsA[d], vm = vsB[d];                                      \
            _Pragma("unroll")                                                    \
            for (int r = 0; r < 4; ++r)                                          \
                outa[r][db] = fmaf(vs, (float)cv[r],                             \
                                   fmaf(vm, c1f[r], outa[r][db]));               \
        }                                                                        \
    }                                                                            \
  } while (0)

    {
        int kt;
        for (kt = 0; kt < kt_end; ++kt) P2_TILE(false);
        kt = kt_end;
        if (causal) P2_TILE(true); else P2_TILE(false);
    }

    // ---- epilogue: out = psc*(outa + cgs) + pmin*vsum ----
    float pscr[4], pmnr[4];
    #pragma unroll
    for (int r = 0; r < 4; ++r) {
        int qq = 16*w + 4*quad + r;
        pscr[r] = rs_psc[qq]; pmnr[r] = rs_pmn[qq];
    }
    #pragma unroll
    for (int db = 0; db < 8; ++db) {
        int d = 16*db + n;
        float vsum = vsumL[d];
        float cgs  = cgsL[d];
        #pragma unroll
        for (int r = 0; r < 4; ++r) {
            int s = s0 + 16*w + 4*quad + r;
            OUT[(size_t)s*RSTR + boff + d] = fmaf(pscr[r], outa[r][db] + cgs, pmnr[r]*vsum);
        }
    }
}

extern "C" void kernel_launch(void* const* d_in, const int* in_sizes, int n_in,
                              void* d_out, int out_size, void* d_ws, size_t ws_size,
                              hipStream_t stream) {
    (void)in_sizes; (void)n_in; (void)out_size; (void)ws_size;
    const float* Q   = (const float*)d_in[0];
    const float* K   = (const float*)d_in[1];
    const float* V   = (const float*)d_in[2];
    const float* QMN = (const float*)d_in[3];
    const float* QSC = (const float*)d_in[4];
    const float* KMN = (const float*)d_in[5];
    const float* KSC = (const float*)d_in[6];
    const float* VMN = (const float*)d_in[7];
    const float* VSC = (const float*)d_in[8];
    const int*   CS  = (const int*)d_in[9];
    float* out = (float*)d_out;

    char* ws = (char*)d_ws;
    signed char* K8  = (signed char*)(ws + WS_K8);
    signed char* V8T = (signed char*)(ws + WS_V8T);
    float* SQs  = (float*)(ws + WS_SQ);
    float* SKs  = (float*)(ws + WS_SK);
    float* GSVp = (float*)(ws + WS_GSV);

    prep_pack<<<16384 + 512, 256, 0, stream>>>(Q, K, V, K8, SQs, SKs, V8T, GSVp);
    attn_main<<<1024, 256, 0, stream>>>(Q, K8, V8T, QMN, QSC, KMN, KSC, VMN, VSC,
                                        SQs, SKs, GSVp, CS, out);
}